// Round 5
// baseline (156.579 us; speedup 1.0000x reference)
//
#include <hip/hip_runtime.h>
#include <hip/hip_bf16.h>

// Lovasz loss via bucketed counting-sort reformulation.
// R2: LDS-private histograms replaced global atomics (1917 -> 219 us).
// R3: parallel merge kernel, float scan (219 -> 154; hist 42 us).
// R4: cooperative single-dispatch fusion: NEUTRAL (150 us) -- grid.sync on
//     2048 blocks costs ~30 us each; fusion via coop is a dead end.
// R5: two plain dispatches, zero grid syncs. hist (8 blocks/CU, inits
//     accumulators) -> mergescan (64 blocks x 1024 threads; merge 64 slices
//     coalesced into LDS with 16 waves/block, scan, last-block-done final).

#define NB    2048      // buckets; worst-case final err 3.8e-5 << 1.67e-4
#define NSEG  64        // C*N
#define PLOG  18        // P = 262144
#define NN    32
#define PTOT  (1 << PLOG)
#define B0_LO (NB / 4)      // mask0: x>0.25  <=> bucket >= NB/4
#define B1_HI (3 * NB / 4)  // mask1: x>0.25  <=> bucket <  3*NB/4
#define ST    1024          // mergescan block size
#define SCH   (NB / ST)     // buckets per thread in the scan (=2)

// partial layout: [n][slice][c][b] u32 packed (n1<<16)|n0, slice in [0,Bn).

// ---------------- Kernel 1: LDS histogram (+ accumulator init) ----------------
__global__ __launch_bounds__(256, 8) void hist_k(
    const float* __restrict__ x, const int* __restrict__ tgt,
    unsigned* __restrict__ partial, float* __restrict__ loss_sum,
    unsigned* __restrict__ valid_cnt, unsigned* __restrict__ done, int Bn)
{
    __shared__ unsigned hl[2 * NB];   // 16 KB
    const int g   = blockIdx.x;
    const int n   = g / Bn;
    const int sl  = g - n * Bn;
    const int tid = threadIdx.x;

    if (g == 0 && tid == 0) {         // ws is 0xAA-poisoned before every call
        *loss_sum = 0.0f; *valid_cnt = 0u; *done = 0u;
    }

    for (int i = tid; i < 2 * NB; i += 256) hl[i] = 0;
    __syncthreads();

    const int pairs = PTOT / Bn;      // 4096 at Bn=64 -> u16 fields safe
    const int base  = sl * pairs;
    const float* x0 = x + (((long long)n * 2) << PLOG);
    const float* x1 = x0 + PTOT;
    const int*   tg = tgt + ((long long)n << PLOG);

    for (int off = tid * 4; off < pairs; off += 256 * 4) {
        const int p = base + off;
        float4 a  = *(const float4*)(x0 + p);
        float4 b  = *(const float4*)(x1 + p);
        int4   t4 = *(const int4*)(tg + p);
        float xa[4] = {a.x, a.y, a.z, a.w};
        float xb[4] = {b.x, b.y, b.z, b.w};
        int   tt[4] = {t4.x, t4.y, t4.z, t4.w};
#pragma unroll
        for (int k = 0; k < 4; ++k) {
            const bool m0 = (tt[k] == 0);
            const bool m1 = (tt[k] == 1);
            float d0 = m0 ? 1.0f - xa[k] : xa[k];
            float d1 = m1 ? 1.0f - xb[k] : xb[k];
            int b0 = min((int)(d0 * (float)NB), NB - 1);
            int b1 = min((int)(d1 * (float)NB), NB - 1);
            atomicAdd(&hl[b0],      m0 ? 0x10000u : 1u);
            atomicAdd(&hl[NB + b1], m1 ? 0x10000u : 1u);
        }
    }
    __syncthreads();   // all LDS atomics visible before flush
    unsigned* outp = partial + (size_t)g * (2 * NB);
    for (int i = tid; i < 2 * NB; i += 256) outp[i] = hl[i];
}

// ------- Kernel 2: merge slices + scan + last-block final (64 x 1024) -------
__global__ __launch_bounds__(ST) void mergescan_k(
    const unsigned* __restrict__ partial, const float* __restrict__ cw,
    const float* __restrict__ tw, float* __restrict__ loss_sum,
    unsigned* __restrict__ valid_cnt, unsigned* __restrict__ done,
    float* __restrict__ out, int Bn)
{
    const int seg = blockIdx.x;           // seg = (c<<5)|n
    const int c = seg >> 5, n = seg & 31;
    const int tid = threadIdx.x;

    __shared__ unsigned mh0[NB], mh1[NB];          // 16 KB merged counts
    __shared__ unsigned sa[ST], s1[ST], sc[ST];    // 12 KB scan arrays

    // Merge: coalesced reads (consecutive tids -> consecutive buckets),
    // 16 waves/block hide the ~200-cycle L2 latency over Bn iterations.
    for (int b = tid; b < NB; b += ST) {
        unsigned v0 = 0, v1 = 0;
        for (int s = 0; s < Bn; ++s) {
            unsigned v = partial[(((size_t)(n * Bn + s) * 2) + c) * NB + b];
            v0 += v & 0xFFFFu; v1 += v >> 16;
        }
        mh0[b] = v0; mh1[b] = v1;
    }
    __syncthreads();

    // Pass A: per-thread totals over descending chunk (+ x>0.25 count).
    unsigned tot_all = 0, tot1 = 0, cgt = 0;
    int maxb_local = -1;
    for (int j = 0; j < SCH; ++j) {
        int b = (NB - 1) - (tid * SCH + j);
        unsigned n0 = mh0[b], n1 = mh1[b];
        tot_all += n0 + n1; tot1 += n1;
        if (b >= B0_LO) cgt += n0;   // mask0: d=x,   x>0.25
        if (b <  B1_HI) cgt += n1;   // mask1: d=1-x, x>0.25 <=> d<0.75
        if (maxb_local < 0 && (n0 | n1)) maxb_local = b;
    }
    sa[tid] = tot_all; s1[tid] = tot1; sc[tid] = cgt;
    __syncthreads();
    for (int off = 1; off < ST; off <<= 1) {   // Hillis-Steele inclusive scan
        unsigned va = 0, v1 = 0, vc = 0;
        if (tid >= off) { va = sa[tid - off]; v1 = s1[tid - off]; vc = sc[tid - off]; }
        __syncthreads();
        sa[tid] += va; s1[tid] += v1; sc[tid] += vc;
        __syncthreads();
    }
    const unsigned gts   = s1[ST - 1];
    const unsigned cntgt = sc[ST - 1];
    const unsigned i0  = (tid > 0) ? sa[tid - 1] : 0;
    const unsigned sc0 = (tid > 0) ? s1[tid - 1] : 0;
    __syncthreads();
    ((int*)sc)[tid] = maxb_local;              // max nonempty bucket
    __syncthreads();
    for (int off = ST / 2; off > 0; off >>= 1) {
        if (tid < off) ((int*)sc)[tid] = max(((int*)sc)[tid], ((int*)sc)[tid + off]);
        __syncthreads();
    }
    const int max_b = ((int*)sc)[0];

    // Pass B: closed-form per-bucket contribution with running (i, s).
    // counts <= 2^18 are float-exact; rel err ~1e-7/term.
    float per_local = 0.0f;
    if (gts > 0) {
        unsigned i = i0, s = sc0;
        for (int j = 0; j < SCH; ++j) {
            int b = (NB - 1) - (tid * SCH + j);
            unsigned n0 = mh0[b], n1 = mh1[b];
            if (n0 | n1) {
                float d_rep = ((float)b + 0.5f) * (1.0f / (float)NB);
                float U = (float)(gts + i - s);
                if (n1) per_local += (float)n1 * d_rep / U;
                s += n1;
                unsigned inter = gts - s;
                if (n0 && inter)
                    per_local += d_rep * (float)inter * (float)n0 /
                                 (U * (U + (float)n0));
                i += n0 + n1;
            }
        }
    }
    __syncthreads();
    float* sd = (float*)sa;    // reuse scan array for the float reduce
    sd[tid] = per_local;
    __syncthreads();
    for (int off = ST / 2; off > 0; off >>= 1) {
        if (tid < off) sd[tid] += sd[tid + off];
        __syncthreads();
    }

    if (tid == 0) {
        float per = sd[0];
        if (gts == 0)
            per = (max_b >= 0) ? ((float)max_b + 0.5f) * (1.0f / (float)NB) : 0.0f;
        const bool empty = (gts == 0) && (cntgt == 0);
        const float cwv = cw[c], twv = tw[n];
        const bool valid = (cwv != 0.0f) && !empty;
        if (valid) {
            atomicAdd(loss_sum, per * twv * cwv);   // device-scope, XCD-safe
            atomicAdd(valid_cnt, 1u);
        }
        __threadfence();
        unsigned old = atomicAdd(done, 1u);         // last block finalizes
        if (old == NSEG - 1) {
            float    L = atomicAdd(loss_sum, 0.0f); // coherent atomic readback
            unsigned V = atomicAdd(valid_cnt, 0u);
            out[0] = L / (float)NN / (float)V;
        }
    }
}

extern "C" void kernel_launch(void* const* d_in, const int* in_sizes, int n_in,
                              void* d_out, int out_size, void* d_ws, size_t ws_size,
                              hipStream_t stream)
{
    const float* x   = (const float*)d_in[0];   // [32,2,512,512] f32
    const int*   tgt = (const int*)d_in[1];     // [32,512,512] int
    const float* cw  = (const float*)d_in[2];   // [2]
    const float* tw  = (const float*)d_in[3];   // [32]
    float* out = (float*)d_out;

    // ws layout: [0,4) loss_sum f32, [4,8) valid_cnt u32, [8,12) done u32,
    // [512, 512 + NN*Bn*2*NB*4) partial. Bn=64 -> 32 MiB (proven fits, R2-R4).
    float*    loss_sum  = (float*)d_ws;
    unsigned* valid_cnt = (unsigned*)((char*)d_ws + 4);
    unsigned* done      = (unsigned*)((char*)d_ws + 8);
    unsigned* partial   = (unsigned*)((char*)d_ws + 512);

    const size_t per_bn = (size_t)NN * 2 * NB * sizeof(unsigned);  // 0.5 MiB
    int Bn;
    if      (ws_size >= 512 + 64 * per_bn) Bn = 64;  // 32 MiB
    else if (ws_size >= 512 + 32 * per_bn) Bn = 32;  // 16 MiB
    else                                   Bn = 16;  //  8 MiB min

    hist_k     <<<NN * Bn, 256, 0, stream>>>(x, tgt, partial, loss_sum,
                                             valid_cnt, done, Bn);
    mergescan_k<<<NSEG, ST, 0, stream>>>(partial, cw, tw, loss_sum,
                                         valid_cnt, done, out, Bn);
}

// Round 6
// 134.470 us; speedup vs baseline: 1.1644x; 1.1644x over previous
//
#include <hip/hip_runtime.h>
#include <hip/hip_bf16.h>

// Lovasz loss via bucketed counting-sort reformulation.
// R2: LDS-private histograms replaced global atomics (1917 -> 219 us).
// R3: parallel merge kernel, float scan (219 -> 154; hist 42 us).
// R4: cooperative single-dispatch fusion NEUTRAL (grid.sync ~30 us each).
// R5: two plain dispatches (156.6). rocprof shows harness ws re-poison fill
//     (256 MiB, 41 us) + input restores ~= 70-85 us FIXED inside the timed
//     window; controllable kernel budget is only ~75 us.
// R6: NB 1024 (partial 32->16 MiB), Bn=64 compile-time (full unroll),
//     mergescan with 1 bucket/thread in registers + shfl scans (2 barriers
//     instead of ~60).

#define NB    1024      // buckets; worst-case final err 7.6e-5 < 1.67e-4
#define NSEG  64        // C*N
#define PLOG  18        // P = 262144
#define NN    32
#define PTOT  (1 << PLOG)
#define BN    64            // slices per sample (compile-time)
#define B0_LO (NB / 4)      // mask0: x>0.25  <=> bucket >= NB/4
#define B1_HI (3 * NB / 4)  // mask1: x>0.25  <=> bucket <  3*NB/4
#define ST    1024          // mergescan block size == NB (1 bucket/thread)

// partial layout: [n][slice][c][b] u32 packed (n1<<16)|n0, slice in [0,BN).
// addr(n,s,c,b) = ((n*BN+s)*2 + c)*NB + b

// ---------------- Kernel 1: LDS histogram (+ accumulator init) --------------
__global__ __launch_bounds__(256, 8) void hist_k(
    const float* __restrict__ x, const int* __restrict__ tgt,
    unsigned* __restrict__ partial, float* __restrict__ loss_sum,
    unsigned* __restrict__ valid_cnt, unsigned* __restrict__ done)
{
    __shared__ unsigned hl[2 * NB];   // 8 KB
    const int g   = blockIdx.x;
    const int n   = g >> 6;           // g / BN
    const int sl  = g & (BN - 1);
    const int tid = threadIdx.x;

    if (g == 0 && tid == 0) {         // ws is 0xAA-poisoned before every call
        *loss_sum = 0.0f; *valid_cnt = 0u; *done = 0u;
    }

    for (int i = tid; i < 2 * NB; i += 256) hl[i] = 0;
    __syncthreads();

    const int pairs = PTOT / BN;      // 4096 -> per-slice bucket count <= 4096
    const int base  = sl * pairs;
    const float* x0 = x + (((long long)n * 2) << PLOG);
    const float* x1 = x0 + PTOT;
    const int*   tg = tgt + ((long long)n << PLOG);

#pragma unroll
    for (int it = 0; it < pairs / (256 * 4); ++it) {     // 4 iterations
        const int p = base + it * 256 * 4 + tid * 4;
        float4 a  = *(const float4*)(x0 + p);
        float4 b  = *(const float4*)(x1 + p);
        int4   t4 = *(const int4*)(tg + p);
        float xa[4] = {a.x, a.y, a.z, a.w};
        float xb[4] = {b.x, b.y, b.z, b.w};
        int   tt[4] = {t4.x, t4.y, t4.z, t4.w};
#pragma unroll
        for (int k = 0; k < 4; ++k) {
            const bool m0 = (tt[k] == 0);
            const bool m1 = (tt[k] == 1);
            float d0 = m0 ? 1.0f - xa[k] : xa[k];
            float d1 = m1 ? 1.0f - xb[k] : xb[k];
            int b0 = min((int)(d0 * (float)NB), NB - 1);
            int b1 = min((int)(d1 * (float)NB), NB - 1);
            atomicAdd(&hl[b0],      m0 ? 0x10000u : 1u);
            atomicAdd(&hl[NB + b1], m1 ? 0x10000u : 1u);
        }
    }
    __syncthreads();   // all LDS atomics visible before flush
    unsigned* outp = partial + (size_t)g * (2 * NB);
    for (int i = tid; i < 2 * NB; i += 256) outp[i] = hl[i];
}

// ------- Kernel 2: merge + scan + last-block final (64 x 1024) --------------
// Thread tid owns bucket b = NB-1-tid (descending order), so "elements in
// higher buckets" is a plain exclusive prefix over tid. All counts live in
// registers; scans via wave shfl + one 16-entry cross-wave pass.
__global__ __launch_bounds__(ST) void mergescan_k(
    const unsigned* __restrict__ partial, const float* __restrict__ cw,
    const float* __restrict__ tw, float* __restrict__ loss_sum,
    unsigned* __restrict__ valid_cnt, unsigned* __restrict__ done,
    float* __restrict__ out)
{
    const int seg = blockIdx.x;           // seg = (c<<5)|n
    const int c = seg >> 5, n = seg & 31;
    const int tid  = threadIdx.x;
    const int lane = tid & 63;
    const int wid  = tid >> 6;            // 16 waves

    // ---- merge 64 slices for this bucket (coalesced u32 loads) ----
    const int b = NB - 1 - tid;
    const unsigned* basep = partial + (((size_t)(n * BN) * 2) + c) * NB + b;
    unsigned n0 = 0, n1 = 0;
#pragma unroll 16
    for (int s = 0; s < BN; ++s) {
        unsigned v = basep[(size_t)s * (2 * NB)];
        n0 += v & 0xFFFFu; n1 += v >> 16;
    }
    const unsigned tot = n0 + n1;

    // ---- wave-level inclusive scans of tot and n1 ----
    unsigned iA = tot, iS = n1;
#pragma unroll
    for (int off = 1; off < 64; off <<= 1) {
        unsigned tA = __shfl_up(iA, off, 64);
        unsigned tS = __shfl_up(iS, off, 64);
        if (lane >= off) { iA += tA; iS += tS; }
    }
    __shared__ unsigned wA[16], wS[16], wC[16];
    __shared__ int      wM[16];
    __shared__ float    wF[16];
    if (lane == 63) { wA[wid] = iA; wS[wid] = iS; }

    // ---- per-wave reduces for cgt (x>0.25 count) and max nonempty bucket ----
    unsigned cgt = ((b >= B0_LO) ? n0 : 0u) + ((b < B1_HI) ? n1 : 0u);
    int mb = (n0 | n1) ? b : -1;
#pragma unroll
    for (int off = 1; off < 64; off <<= 1) {
        cgt += __shfl_xor(cgt, off, 64);
        mb = max(mb, __shfl_xor(mb, off, 64));
    }
    if (lane == 0) { wC[wid] = cgt; wM[wid] = mb; }
    __syncthreads();

    // ---- cross-wave scan of the 16 wave sums (done in wave 0) ----
    if (tid < 16) {
        unsigned a = wA[tid], s2 = wS[tid];
#pragma unroll
        for (int off = 1; off < 16; off <<= 1) {
            unsigned tA = __shfl_up(a, off, 64);
            unsigned tS = __shfl_up(s2, off, 64);
            if (tid >= off) { a += tA; s2 += tS; }
        }
        wA[tid] = a; wS[tid] = s2;   // inclusive wave prefix
    }
    __syncthreads();

    const unsigned gts   = wS[15];
    const unsigned exclA = iA - tot + (wid ? wA[wid - 1] : 0u);
    const unsigned exclS = iS - n1  + (wid ? wS[wid - 1] : 0u);

    // ---- closed-form per-bucket contribution (counts <= 2^18, float-exact) --
    float per_local = 0.0f;
    if (gts > 0 && (n0 | n1)) {
        float d_rep = ((float)b + 0.5f) * (1.0f / (float)NB);
        float U = (float)(gts + exclA - exclS);
        if (n1) per_local += (float)n1 * d_rep / U;
        unsigned s = exclS + n1;
        unsigned inter = gts - s;
        if (n0 && inter)
            per_local += d_rep * (float)inter * (float)n0 /
                         (U * (U + (float)n0));
    }
#pragma unroll
    for (int off = 1; off < 64; off <<= 1)
        per_local += __shfl_xor(per_local, off, 64);
    if (lane == 0) wF[wid] = per_local;
    __syncthreads();

    if (tid == 0) {
        float per = 0.0f;
        unsigned cntgt = 0;
        int max_b = -1;
        for (int i = 0; i < 16; ++i) {
            per += wF[i]; cntgt += wC[i]; max_b = max(max_b, wM[i]);
        }
        if (gts == 0)
            per = (max_b >= 0) ? ((float)max_b + 0.5f) * (1.0f / (float)NB) : 0.0f;
        const bool empty = (gts == 0) && (cntgt == 0);
        const float cwv = cw[c], twv = tw[n];
        const bool valid = (cwv != 0.0f) && !empty;
        if (valid) {
            atomicAdd(loss_sum, per * twv * cwv);   // device-scope, XCD-safe
            atomicAdd(valid_cnt, 1u);
        }
        __threadfence();
        unsigned old = atomicAdd(done, 1u);         // last block finalizes
        if (old == NSEG - 1) {
            float    L = atomicAdd(loss_sum, 0.0f); // coherent atomic readback
            unsigned V = atomicAdd(valid_cnt, 0u);
            out[0] = L / (float)NN / (float)V;
        }
    }
}

extern "C" void kernel_launch(void* const* d_in, const int* in_sizes, int n_in,
                              void* d_out, int out_size, void* d_ws, size_t ws_size,
                              hipStream_t stream)
{
    const float* x   = (const float*)d_in[0];   // [32,2,512,512] f32
    const int*   tgt = (const int*)d_in[1];     // [32,512,512] int
    const float* cw  = (const float*)d_in[2];   // [2]
    const float* tw  = (const float*)d_in[3];   // [32]
    float* out = (float*)d_out;

    // ws layout: [0,4) loss_sum f32, [4,8) valid_cnt u32, [8,12) done u32,
    // [512, 512 + NN*BN*2*NB*4 = 16 MiB) partial. (ws proven >= 32 MiB, R2-R5.)
    float*    loss_sum  = (float*)d_ws;
    unsigned* valid_cnt = (unsigned*)((char*)d_ws + 4);
    unsigned* done      = (unsigned*)((char*)d_ws + 8);
    unsigned* partial   = (unsigned*)((char*)d_ws + 512);

    hist_k     <<<NN * BN, 256, 0, stream>>>(x, tgt, partial, loss_sum,
                                             valid_cnt, done);
    mergescan_k<<<NSEG, ST, 0, stream>>>(partial, cw, tw, loss_sum,
                                         valid_cnt, done, out);
}